// Round 1
// baseline (250.031 us; speedup 1.0000x reference)
//
#include <hip/hip_runtime.h>
#include <stdint.h>

typedef _Float16 h8 __attribute__((ext_vector_type(8)));
typedef _Float16 h4 __attribute__((ext_vector_type(4)));
typedef float f32x4 __attribute__((ext_vector_type(4)));

// workspace byte offsets (total ~49 MB)
#define WS_WC   0u          // _Float16 [384][1024] combined weights
#define WS_BIAS 786432u     // float [384] combined bias
#define WS_FT   1048576u    // _Float16 [4][4096][1024] feats^T
#define WS_QKVT 34603008u   // _Float16 [4][4096][384]  q|k|v, n-major
#define WS_VT   47185920u   // _Float16 [4][128][4096]  v, d-major

// ---------------- kernel 0: fold projections: Wc = [w1;w2;w3] @ PW ----------------
__global__ void k_weights(const float* __restrict__ pw, const float* __restrict__ pb,
                          const float* __restrict__ w1, const float* __restrict__ b1,
                          const float* __restrict__ w2, const float* __restrict__ b2,
                          const float* __restrict__ w3, const float* __restrict__ b3,
                          _Float16* __restrict__ Wc, float* __restrict__ bc)
{
  int idx = blockIdx.x * 256 + threadIdx.x;          // 384*1024 total
  int o3 = idx >> 10, ck = idx & 1023;
  const float* wg = (o3 < 128) ? w1 : (o3 < 256 ? w2 : w3);
  int o = o3 & 127;
  float s = 0.f;
  #pragma unroll 8
  for (int c = 0; c < 128; ++c) s += wg[o * 128 + c] * pw[c * 1024 + ck];
  Wc[idx] = (_Float16)s;
  if (idx < 384) {
    const float* wgb = (idx < 128) ? w1 : (idx < 256 ? w2 : w3);
    const float* bg  = (idx < 128) ? b1 : (idx < 256 ? b2 : b3);
    int oo = idx & 127;
    float sb = bg[oo];
    for (int c = 0; c < 128; ++c) sb += wgb[oo * 128 + c] * pb[c];
    bc[idx] = sb;
  }
}

// ---------------- kernel 1: feats (b,1024,4096) f32 -> feats^T (b,4096,1024) fp16 ----------------
__global__ void k_featT(const float* __restrict__ feats, _Float16* __restrict__ FT)
{
  __shared__ float tile[64][65];                     // +1 pad: conflict-free column reads
  const int ck0 = blockIdx.x * 64, n0 = blockIdx.y * 64, b = blockIdx.z;
  const int t = threadIdx.x;
  const float* src = feats + ((size_t)(b * 1024 + ck0)) * 4096 + n0;
  #pragma unroll
  for (int p = 0; p < 4; ++p) {
    int i = t + p * 256, row = i >> 4, slot = i & 15; // row=ck, 4 floats per slot
    float4 g = *(const float4*)(src + (size_t)row * 4096 + slot * 4);
    tile[row][slot * 4 + 0] = g.x; tile[row][slot * 4 + 1] = g.y;
    tile[row][slot * 4 + 2] = g.z; tile[row][slot * 4 + 3] = g.w;
  }
  __syncthreads();
  _Float16* dst = FT + ((size_t)(b * 4096 + n0)) * 1024 + ck0;
  #pragma unroll
  for (int p = 0; p < 4; ++p) {
    int i = t + p * 256, n = i >> 4, cs = i & 15;
    h4 o;
    #pragma unroll
    for (int j = 0; j < 4; ++j) o[j] = (_Float16)tile[cs * 4 + j][n];
    *(h4*)(dst + (size_t)n * 1024 + cs * 4) = o;
  }
}

// ---------------- kernel 2: qkvt[b][n][o] = FT[b][n][:] . Wc[o][:] + bias[o] ----------------
// M=4096(n) x N=384(o) x K=1024. BM=BN=128, BK=64, 4 waves (2x2), 16x16x32 fp16 MFMA.
__global__ __launch_bounds__(256) void k_gemm(const _Float16* __restrict__ FT,
                                              const _Float16* __restrict__ Wc,
                                              const float* __restrict__ bc,
                                              _Float16* __restrict__ qkvt)
{
  extern __shared__ char smem[];                     // 2 bufs x (A 16K + W 16K) = 64K
  const int t = threadIdx.x, lane = t & 63, w = t >> 6;
  const int lo = lane & 15, hi = lane >> 4;
  const int bx = blockIdx.x, by = blockIdx.y, bz = blockIdx.z;
  const int n0 = by * 128;
  const int wr = w >> 1, wc = w & 1;
  const int nb_ = wr * 64, ob_ = wc * 64;

  uint4 areg[4], wreg[4];
  const char* Fbase = (const char*)FT + ((size_t)(bz * 4096 + n0)) * 2048;
  const char* Wbase = (const char*)Wc + ((size_t)(bx * 128)) * 2048;

  auto stageload = [&](int s) {
    const char* Fb = Fbase + s * 128;
    const char* Wb = Wbase + s * 128;
    #pragma unroll
    for (int p = 0; p < 4; ++p) {
      int i = t + p * 256, row = i >> 3, slot = i & 7;
      areg[p] = *(const uint4*)(Fb + (size_t)row * 2048 + slot * 16);
      wreg[p] = *(const uint4*)(Wb + (size_t)row * 2048 + slot * 16);
    }
  };
  auto stagewrite = [&](int buf) {
    char* base = smem + buf * 32768;
    #pragma unroll
    for (int p = 0; p < 4; ++p) {
      int i = t + p * 256, row = i >> 3, slot = i & 7;
      int off = row * 128 + ((slot * 16) ^ ((row & 7) << 4));
      *(uint4*)(base + off) = areg[p];
      *(uint4*)(base + 16384 + off) = wreg[p];
    }
  };

  const f32x4 zero4 = {0.f, 0.f, 0.f, 0.f};
  f32x4 acc[4][4];
  #pragma unroll
  for (int i2 = 0; i2 < 4; ++i2)
    #pragma unroll
    for (int j2 = 0; j2 < 4; ++j2) acc[i2][j2] = zero4;

  stageload(0); stagewrite(0);
  for (int s = 0; s < 16; ++s) {
    __syncthreads();
    if (s < 15) stageload(s + 1);
    const char* base = smem + (s & 1) * 32768;
    #pragma unroll
    for (int kk = 0; kk < 2; ++kk) {
      const int cb = kk * 64 + hi * 16;
      h8 af[4], bf[4];
      #pragma unroll
      for (int i2 = 0; i2 < 4; ++i2) {
        int row = nb_ + i2 * 16 + lo;
        af[i2] = *(const h8*)(base + row * 128 + (cb ^ ((row & 7) << 4)));
      }
      #pragma unroll
      for (int j2 = 0; j2 < 4; ++j2) {
        int row = ob_ + j2 * 16 + lo;
        bf[j2] = *(const h8*)(base + 16384 + row * 128 + (cb ^ ((row & 7) << 4)));
      }
      #pragma unroll
      for (int i2 = 0; i2 < 4; ++i2)
        #pragma unroll
        for (int j2 = 0; j2 < 4; ++j2)
          acc[i2][j2] = __builtin_amdgcn_mfma_f32_16x16x32_f16(af[i2], bf[j2], acc[i2][j2], 0, 0, 0);
    }
    if (s < 15) stagewrite((s + 1) & 1);
  }

  float bias[4];
  #pragma unroll
  for (int j2 = 0; j2 < 4; ++j2) bias[j2] = bc[bx * 128 + ob_ + j2 * 16 + lo];
  #pragma unroll
  for (int i2 = 0; i2 < 4; ++i2)
    #pragma unroll
    for (int j2 = 0; j2 < 4; ++j2)
      #pragma unroll
      for (int r = 0; r < 4; ++r) {
        int nrel = n0 + nb_ + i2 * 16 + hi * 4 + r;
        int ocol = bx * 128 + ob_ + j2 * 16 + lo;
        qkvt[((size_t)(bz * 4096 + nrel)) * 384 + ocol] = (_Float16)(acc[i2][j2][r] + bias[j2]);
      }
}

// ---------------- kernel 3: v slice of qkvt (n-major) -> v_t[b][d][m] (d-major) ----------------
__global__ void k_vtrans(const _Float16* __restrict__ qkvt, _Float16* __restrict__ vt)
{
  __shared__ char tl[64 * 256];                      // [m 64][d 128] fp16, swizzled
  const int mt = blockIdx.x, b = blockIdx.y, t = threadIdx.x;
  const int m0 = mt * 64;
  #pragma unroll
  for (int p = 0; p < 4; ++p) {
    int i = t + p * 256, m = i >> 4, slot = i & 15;
    uint4 g = *(const uint4*)((const char*)qkvt + ((size_t)(b * 4096 + m0 + m)) * 768 + 512 + slot * 16);
    *(uint4*)(tl + m * 256 + ((slot * 16) ^ ((m & 7) << 4))) = g;
  }
  __syncthreads();
  #pragma unroll
  for (int p = 0; p < 8; ++p) {
    int i = t + p * 256, d = i >> 4, ms = i & 15;
    h4 o;
    #pragma unroll
    for (int j = 0; j < 4; ++j) {
      int m = ms * 4 + j;
      o[j] = *(const _Float16*)(tl + m * 256 + ((2 * d) ^ ((m & 7) << 4)));
    }
    *(h4*)((char*)vt + ((size_t)(b * 128 + d)) * 8192 + (m0 + ms * 4) * 2) = o;
  }
}

// ---------------- kernel 4: flash attention, O^T = V^T P^T, out f32 (b,d,n) ----------------
// 64 queries/block, 4 waves x 16 q-rows, KB=64 keys/iter, fp16 MFMA, fp32 online softmax.
#define ATT_LDS 90112
__global__ __launch_bounds__(256) void k_attn(const _Float16* __restrict__ qkvt,
                                              const _Float16* __restrict__ vt,
                                              float* __restrict__ out)
{
  extern __shared__ char smem[];
  // [0,16K) Q[64][128];  16K + buf*32K: K[64][128], +16K: V[128][64];  81920: P[4][16][64]
  const int t = threadIdx.x, lane = t & 63, w = t >> 6;
  const int lo = lane & 15, hi = lane >> 4;
  // bijective XCD swizzle: batch b pinned to XCDs {2b, 2b+1} so its 2MB K/V L2-fits
  const int id = blockIdx.x;
  const int qtile = ((id >> 3) << 1) | (id & 1);
  const int b = (id >> 1) & 3;
  const int n0 = qtile * 64;
  const char* qbase = (const char*)qkvt + (size_t)b * 4096 * 768;
  const char* vbase = (const char*)vt + (size_t)b * 128 * 8192;

  // stage Q once
  #pragma unroll
  for (int p = 0; p < 4; ++p) {
    int i = t + p * 256, row = i >> 4, slot = i & 15;
    uint4 g = *(const uint4*)(qbase + (size_t)(n0 + row) * 768 + slot * 16);
    *(uint4*)(smem + row * 256 + ((slot * 16) ^ ((row & 7) << 4))) = g;
  }

  uint4 kreg[4], vreg[4];
  auto kvload = [&](int it) {
    const int m0 = it * 64;
    #pragma unroll
    for (int p = 0; p < 4; ++p) {
      int i = t + p * 256;
      int krow = i >> 4, kslot = i & 15;
      kreg[p] = *(const uint4*)(qbase + (size_t)(m0 + krow) * 768 + 256 + kslot * 16);
      int vrow = i >> 3, vslot = i & 7;
      vreg[p] = *(const uint4*)(vbase + (size_t)vrow * 8192 + m0 * 2 + vslot * 16);
    }
  };
  auto kvwrite = [&](int buf) {
    char* kb = smem + 16384 + buf * 32768;
    char* vb = kb + 16384;
    #pragma unroll
    for (int p = 0; p < 4; ++p) {
      int i = t + p * 256;
      int krow = i >> 4, kslot = i & 15;
      *(uint4*)(kb + krow * 256 + ((kslot * 16) ^ ((krow & 7) << 4))) = kreg[p];
      int vrow = i >> 3, vslot = i & 7;
      *(uint4*)(vb + vrow * 128 + ((vslot * 16) ^ ((vrow & 7) << 4))) = vreg[p];
    }
  };

  kvload(0); kvwrite(0);
  __syncthreads();

  // hoist Q fragments (wave-private rows w*16+lo)
  h8 aq[4];
  {
    const int qrow = w * 16 + lo, qsw = (qrow & 7) << 4;
    #pragma unroll
    for (int dk = 0; dk < 4; ++dk)
      aq[dk] = *(const h8*)(smem + qrow * 256 + ((dk * 64 + hi * 16) ^ qsw));
  }

  const f32x4 zero4 = {0.f, 0.f, 0.f, 0.f};
  float m_run[4], l_run[4];
  #pragma unroll
  for (int r = 0; r < 4; ++r) { m_run[r] = -1e30f; l_run[r] = 0.f; }
  f32x4 oacc[8];
  #pragma unroll
  for (int dt = 0; dt < 8; ++dt) oacc[dt] = zero4;

  char* pmine = smem + 81920 + w * 2048;             // per-wave P [16][64] fp16 swizzled
  const int rq = lo & 3;
  const int bsrc = (lo >> 2) << 4;                   // broadcast source lane for col-layout

  for (int it = 0; it < 64; ++it) {
    if (it < 63) kvload(it + 1);
    const char* kb = smem + 16384 + (it & 1) * 32768;
    const char* vb = kb + 16384;

    // ---- S = Q K^T  (D[row=q][col=key]) ----
    f32x4 s[4];
    #pragma unroll
    for (int mt = 0; mt < 4; ++mt) s[mt] = zero4;
    #pragma unroll
    for (int dk = 0; dk < 4; ++dk) {
      #pragma unroll
      for (int mt = 0; mt < 4; ++mt) {
        int krow = mt * 16 + lo;
        h8 bk = *(const h8*)(kb + krow * 256 + ((dk * 64 + hi * 16) ^ ((krow & 7) << 4)));
        s[mt] = __builtin_amdgcn_mfma_f32_16x16x32_f16(aq[dk], bk, s[mt], 0, 0, 0);
      }
    }

    // ---- online softmax (rows = queries; 16 lanes hold one row's 16 keys per mt) ----
    float sc[4];
    #pragma unroll
    for (int r = 0; r < 4; ++r) {
      float mx = fmaxf(fmaxf(s[0][r], s[1][r]), fmaxf(s[2][r], s[3][r]));
      mx = fmaxf(mx, __shfl_xor(mx, 1)); mx = fmaxf(mx, __shfl_xor(mx, 2));
      mx = fmaxf(mx, __shfl_xor(mx, 4)); mx = fmaxf(mx, __shfl_xor(mx, 8));
      float mnew = fmaxf(m_run[r], mx);
      sc[r] = __expf(m_run[r] - mnew);
      float p0 = __expf(s[0][r] - mnew), p1 = __expf(s[1][r] - mnew);
      float p2 = __expf(s[2][r] - mnew), p3 = __expf(s[3][r] - mnew);
      float rs = p0 + p1 + p2 + p3;
      rs += __shfl_xor(rs, 1); rs += __shfl_xor(rs, 2);
      rs += __shfl_xor(rs, 4); rs += __shfl_xor(rs, 8);
      l_run[r] = l_run[r] * sc[r] + rs;
      m_run[r] = mnew;
      const int prow = hi * 4 + r, psw = (prow & 7) << 4;
      *(_Float16*)(pmine + prow * 128 + ((2 * (0  + lo)) ^ psw)) = (_Float16)p0;
      *(_Float16*)(pmine + prow * 128 + ((2 * (16 + lo)) ^ psw)) = (_Float16)p1;
      *(_Float16*)(pmine + prow * 128 + ((2 * (32 + lo)) ^ psw)) = (_Float16)p2;
      *(_Float16*)(pmine + prow * 128 + ((2 * (48 + lo)) ^ psw)) = (_Float16)p3;
    }

    // rescale O^T (cols = queries): broadcast per-row scale to col layout
    {
      float c0 = __shfl(sc[0], bsrc), c1 = __shfl(sc[1], bsrc);
      float c2 = __shfl(sc[2], bsrc), c3 = __shfl(sc[3], bsrc);
      float scol = (rq == 0) ? c0 : (rq == 1) ? c1 : (rq == 2) ? c2 : c3;
      #pragma unroll
      for (int dt = 0; dt < 8; ++dt) oacc[dt] *= scol;
    }

    // ---- O^T += V^T P^T  (A = v_lds[d][m], B = p_lds[q][m]) ----
    #pragma unroll
    for (int kk = 0; kk < 2; ++kk) {
      const int prow2 = lo;
      h8 bp = *(const h8*)(pmine + prow2 * 128 + ((kk * 64 + hi * 16) ^ ((prow2 & 7) << 4)));
      #pragma unroll
      for (int dt = 0; dt < 8; ++dt) {
        int vrow = dt * 16 + lo;
        h8 av = *(const h8*)(vb + vrow * 128 + ((kk * 64 + hi * 16) ^ ((vrow & 7) << 4)));
        oacc[dt] = __builtin_amdgcn_mfma_f32_16x16x32_f16(av, bp, oacc[dt], 0, 0, 0);
      }
    }

    if (it < 63) kvwrite((it + 1) & 1);
    __syncthreads();
  }

  // ---- epilogue: normalize and store out[b][d][n] (coalesced along n) ----
  float l0 = __shfl(l_run[0], bsrc), l1 = __shfl(l_run[1], bsrc);
  float l2 = __shfl(l_run[2], bsrc), l3 = __shfl(l_run[3], bsrc);
  float lcol = (rq == 0) ? l0 : (rq == 1) ? l1 : (rq == 2) ? l2 : l3;
  float inv = 1.0f / lcol;
  const int ncol = n0 + w * 16 + lo;
  #pragma unroll
  for (int dt = 0; dt < 8; ++dt)
    #pragma unroll
    for (int r = 0; r < 4; ++r) {
      int d = dt * 16 + hi * 4 + r;
      out[((size_t)(b * 128 + d)) * 4096 + ncol] = oacc[dt][r] * inv;
    }
}

extern "C" void kernel_launch(void* const* d_in, const int* in_sizes, int n_in,
                              void* d_out, int out_size, void* d_ws, size_t ws_size,
                              hipStream_t stream)
{
  const float* feats = (const float*)d_in[0];
  const float* pw = (const float*)d_in[1];
  const float* pb = (const float*)d_in[2];
  const float* w1 = (const float*)d_in[3];
  const float* b1 = (const float*)d_in[4];
  const float* w2 = (const float*)d_in[5];
  const float* b2 = (const float*)d_in[6];
  const float* w3 = (const float*)d_in[7];
  const float* b3 = (const float*)d_in[8];
  char* ws = (char*)d_ws;
  _Float16* Wc = (_Float16*)(ws + WS_WC);
  float* bc = (float*)(ws + WS_BIAS);
  _Float16* FT = (_Float16*)(ws + WS_FT);
  _Float16* qkvt = (_Float16*)(ws + WS_QKVT);
  _Float16* vt = (_Float16*)(ws + WS_VT);
  float* out = (float*)d_out;

  hipLaunchKernelGGL(k_weights, dim3(1536), dim3(256), 0, stream,
                     pw, pb, w1, b1, w2, b2, w3, b3, Wc, bc);
  hipLaunchKernelGGL(k_featT, dim3(16, 64, 4), dim3(256), 0, stream, feats, FT);
  hipLaunchKernelGGL(k_gemm, dim3(3, 32, 4), dim3(256), 65536, stream, FT, Wc, bc, qkvt);
  hipLaunchKernelGGL(k_vtrans, dim3(64, 4), dim3(256), 0, stream, qkvt, vt);
  hipLaunchKernelGGL(k_attn, dim3(256), dim3(256), ATT_LDS, stream, qkvt, vt, out);
}